// Round 1
// baseline (222.524 us; speedup 1.0000x reference)
//
#include <hip/hip_runtime.h>
#include <math.h>

// ---- static config (mirrors reference) ----
#define BB 16
#define AA 3
#define NCC 80
#define WW 76
#define MM 32
#define CELLS_PER_IMG (AA * WW * WW)          // 17328
#define NDECODE (BB * CELLS_PER_IMG * 85)     // 23,566,080
#define NCELLS (BB * CELLS_PER_IMG)           // 277,248

__constant__ float c_anchor[9][2] = {
    {10.f,13.f},{16.f,30.f},{33.f,23.f},{30.f,61.f},{62.f,45.f},
    {59.f,119.f},{116.f,90.f},{156.f,198.f},{373.f,326.f}};

__device__ __forceinline__ float sigm(float x) { return 1.0f / (1.0f + expf(-x)); }

// ---------------------------------------------------------------------------
// Kernel 1: elementwise decode. decoded flat layout == prediction flat layout
// (reshape is a reinterpretation), so decoded[i] = f(pred[i]) keyed by c=i%85.
//   c==0: sigmoid + h   (arange(W) broadcasts over the LAST axis = h)
//   c==1: sigmoid + w
//   c==2: exp * anchor_w / 608 * 76
//   c==3: exp * anchor_h / 608 * 76
//   c>=4: sigmoid (conf + classes)
// ---------------------------------------------------------------------------
__global__ void decode_kernel(const float* __restrict__ in, float* __restrict__ out) {
    const int n4 = NDECODE / 4;
    int tid = blockIdx.x * blockDim.x + threadIdx.x;
    if (tid >= n4) return;
    float4 v = reinterpret_cast<const float4*>(in)[tid];
    float vals[4] = {v.x, v.y, v.z, v.w};
    float res[4];
    int base = tid * 4;
#pragma unroll
    for (int j = 0; j < 4; ++j) {
        int i = base + j;
        int c = i % 85;
        float x = vals[j];
        float r;
        if (c >= 4) {
            r = sigm(x);
        } else {
            int cell = i / 85;
            if (c == 0) {
                int h = cell % WW;
                r = sigm(x) + (float)h;
            } else if (c == 1) {
                int w = (cell / WW) % WW;
                r = sigm(x) + (float)w;
            } else {
                int a = (cell / (WW * WW)) % AA;
                float an = (c == 2) ? c_anchor[a][0] : c_anchor[a][1];
                r = expf(x) * an / 608.0f * 76.0f;
            }
        }
        res[j] = r;
    }
    float4 o = make_float4(res[0], res[1], res[2], res[3]);
    reinterpret_cast<float4*>(out)[tid] = o;
}

// ---------------------------------------------------------------------------
// Kernel 2: per-cell max-IoU vs the image's 32 GT boxes -> noobj; zero obj.
// Reads box channels (c=0..3) back from decoded. GT boxes staged in LDS.
// blockIdx.y = image b, blockIdx.x covers the 17328 cells.
// ---------------------------------------------------------------------------
__global__ void noobj_kernel(const float* __restrict__ dec, const float* __restrict__ gt,
                             float* __restrict__ noobj, float* __restrict__ obj) {
    __shared__ float4 sbox[MM];
    int b = blockIdx.y;
    int t = threadIdx.x;
    if (t < MM) {
        const float* g = gt + (size_t)(b * MM + t) * 6;
        float cx = g[1], cy = g[2], gw = g[3], gh = g[4];
        sbox[t] = make_float4((cx - gw * 0.5f) * 608.0f, (cy - gh * 0.5f) * 608.0f,
                              (cx + gw * 0.5f) * 608.0f, (cy + gh * 0.5f) * 608.0f);
    }
    __syncthreads();
    int n = blockIdx.x * blockDim.x + t;
    if (n >= CELLS_PER_IMG) return;
    size_t idx = (size_t)b * CELLS_PER_IMG + n;
    const float* p = dec + idx * 85;
    float px = p[0], py = p[1], pw = p[2], ph = p[3];
    // replicate reference FP order: (val)/W * INPUTW
    float x1 = (px - pw * 0.5f) / 76.0f * 608.0f;
    float y1 = (py - ph * 0.5f) / 76.0f * 608.0f;
    float x2 = (px + pw * 0.5f) / 76.0f * 608.0f;
    float y2 = (py + ph * 0.5f) / 76.0f * 608.0f;
    float area2 = (x2 - x1) * (y2 - y1);
    float best = 0.0f;  // iou >= 0 always
#pragma unroll
    for (int m = 0; m < MM; ++m) {
        float4 gb = sbox[m];
        float area1 = (gb.z - gb.x) * (gb.w - gb.y);
        float ltx = fmaxf(gb.x, x1), lty = fmaxf(gb.y, y1);
        float rbx = fminf(gb.z, x2), rby = fminf(gb.w, y2);
        float inter = fmaxf(rbx - ltx, 0.0f) * fmaxf(rby - lty, 0.0f);
        float iou = inter / (area1 + area2 - inter);
        best = fmaxf(best, iou);
    }
    noobj[idx] = (best <= 0.5f) ? 1.0f : 0.0f;
    obj[idx] = 0.0f;
}

// ---------------------------------------------------------------------------
// Kernel 3: per-GT best-anchor assignment (argmax over 9, first-max tiebreak
// like jnp.argmax). valid => obj[flat]=1, noobj[flat]=0. Idempotent constant
// writes -> no atomics needed. Runs after kernel 2 (stream order).
// ---------------------------------------------------------------------------
__global__ void assign_kernel(const float* __restrict__ gt,
                              float* __restrict__ noobj, float* __restrict__ obj) {
    int r = blockIdx.x * blockDim.x + threadIdx.x;
    if (r >= BB * MM) return;
    const float* g = gt + (size_t)r * 6;
    float cx = g[1], cy = g[2], gw = g[3], gh = g[4];
    float gx1 = (cx - gw * 0.5f) * 608.0f, gy1 = (cy - gh * 0.5f) * 608.0f;
    float gx2 = (cx + gw * 0.5f) * 608.0f, gy2 = (cy + gh * 0.5f) * 608.0f;
    float area_g = (gx2 - gx1) * (gy2 - gy1);
    int best = 0;
    float bestv = -1.0f;
#pragma unroll
    for (int k = 0; k < 9; ++k) {
        float ow = c_anchor[k][0] / 608.0f, oh = c_anchor[k][1] / 608.0f;
        float ax1 = (cx - ow * 0.5f) * 608.0f, ay1 = (cy - oh * 0.5f) * 608.0f;
        float ax2 = (cx + ow * 0.5f) * 608.0f, ay2 = (cy + oh * 0.5f) * 608.0f;
        float ltx = fmaxf(gx1, ax1), lty = fmaxf(gy1, ay1);
        float rbx = fminf(gx2, ax2), rby = fminf(gy2, ay2);
        float inter = fmaxf(rbx - ltx, 0.0f) * fmaxf(rby - lty, 0.0f);
        float area_a = (ax2 - ax1) * (ay2 - ay1);
        float v = inter / (area_g + area_a - inter);
        if (v > bestv) { bestv = v; best = k; }
    }
    if (best < AA) {
        int b = r / MM;  // reference uses row position, not the gt batch column
        int gi = (int)(cx * 76.0f);
        int gj = (int)(cy * 76.0f);
        int flat = ((b * AA + best) * WW + gi) * WW + gj;
        obj[flat] = 1.0f;
        noobj[flat] = 0.0f;
    }
}

extern "C" void kernel_launch(void* const* d_in, const int* in_sizes, int n_in,
                              void* d_out, int out_size, void* d_ws, size_t ws_size,
                              hipStream_t stream) {
    const float* pred = (const float*)d_in[0];
    const float* gt   = (const float*)d_in[1];
    float* dec   = (float*)d_out;            // 23,566,080
    float* noobj = dec + NDECODE;            //    277,248
    float* obj   = noobj + NCELLS;           //    277,248

    const int n4 = NDECODE / 4;              // 5,891,520, divisible by 4
    decode_kernel<<<(n4 + 255) / 256, 256, 0, stream>>>(pred, dec);

    dim3 gb((CELLS_PER_IMG + 255) / 256, BB);
    noobj_kernel<<<gb, 256, 0, stream>>>(dec, gt, noobj, obj);

    assign_kernel<<<2, 256, 0, stream>>>(gt, noobj, obj);
}

// Round 2
// 201.606 us; speedup vs baseline: 1.1038x; 1.1038x over previous
//
#include <hip/hip_runtime.h>
#include <math.h>

// ---- static config (mirrors reference) ----
#define BB 16
#define AA 3
#define NCC 80
#define WW 76
#define MM 32
#define CELLS_PER_IMG (AA * WW * WW)          // 17328
#define NDECODE (BB * CELLS_PER_IMG * 85)     // 23,566,080
#define NCELLS (BB * CELLS_PER_IMG)           // 277,248

__constant__ float c_anchor[9][2] = {
    {10.f,13.f},{16.f,30.f},{33.f,23.f},{30.f,61.f},{62.f,45.f},
    {59.f,119.f},{116.f,90.f},{156.f,198.f},{373.f,326.f}};

#define LOG2E 1.4426950408889634f

__device__ __forceinline__ float fast_sigmoid(float x) {
    // 1/(1+exp(-x)) via v_exp_f32 + v_rcp_f32 (~2-3 ulp; threshold is 1.52)
    return __builtin_amdgcn_rcpf(1.0f + __builtin_amdgcn_exp2f(-x * LOG2E));
}

// ---------------------------------------------------------------------------
// Kernel 1: elementwise decode (flat layout identical to input reshape).
//   c==0: sigmoid + h   (arange broadcasts over LAST axis = h)
//   c==1: sigmoid + w
//   c==2/3: exp * anchor / 608 * 76  (= anchor * 0.125)
//   c>=4: sigmoid
// Also scatters box channels (c<4) into a dense boxes[NCELLS][4] buffer so
// the noobj kernel gets coalesced float4 reads instead of 340B-stride gathers.
// ---------------------------------------------------------------------------
__global__ void decode_kernel(const float* __restrict__ in, float* __restrict__ out,
                              float* __restrict__ boxes) {
    const int n4 = NDECODE / 4;
    int tid = blockIdx.x * blockDim.x + threadIdx.x;
    if (tid >= n4) return;
    float4 v = reinterpret_cast<const float4*>(in)[tid];
    float vals[4] = {v.x, v.y, v.z, v.w};
    float res[4];
    int base = tid * 4;
    int c = base % 85;          // one magic-mul per thread
    int cell = base / 85;
#pragma unroll
    for (int j = 0; j < 4; ++j) {
        float x = vals[j];
        float r;
        if (c >= 4) {
            r = fast_sigmoid(x);
        } else {
            if (c < 2) {
                float s = fast_sigmoid(x);
                int q = (c == 0) ? (cell % WW) : ((cell / WW) % WW);
                r = s + (float)q;
            } else {
                int a = (cell / (WW * WW)) % AA;
                float an = (c == 2) ? c_anchor[a][0] : c_anchor[a][1];
                r = __builtin_amdgcn_exp2f(x * LOG2E) * (an * 0.125f);
            }
            boxes[cell * 4 + c] = r;
        }
        res[j] = r;
        if (++c == 85) { c = 0; ++cell; }
    }
    reinterpret_cast<float4*>(out)[tid] = make_float4(res[0], res[1], res[2], res[3]);
}

// ---------------------------------------------------------------------------
// Kernel 2: per-cell max-IoU vs the image's 32 GT boxes -> noobj; zero obj.
// Reads the dense boxes buffer (coalesced float4). GT boxes staged in LDS.
// ---------------------------------------------------------------------------
__global__ void noobj_kernel(const float4* __restrict__ boxes, const float* __restrict__ gt,
                             float* __restrict__ noobj, float* __restrict__ obj) {
    __shared__ float4 sbox[MM];
    int b = blockIdx.y;
    int t = threadIdx.x;
    if (t < MM) {
        const float* g = gt + (size_t)(b * MM + t) * 6;
        float cx = g[1], cy = g[2], gw = g[3], gh = g[4];
        sbox[t] = make_float4((cx - gw * 0.5f) * 608.0f, (cy - gh * 0.5f) * 608.0f,
                              (cx + gw * 0.5f) * 608.0f, (cy + gh * 0.5f) * 608.0f);
    }
    __syncthreads();
    int n = blockIdx.x * blockDim.x + t;
    if (n >= CELLS_PER_IMG) return;
    size_t idx = (size_t)b * CELLS_PER_IMG + n;
    float4 pb = boxes[idx];
    float px = pb.x, py = pb.y, pw = pb.z, ph = pb.w;
    // replicate reference FP order: (val)/W * INPUTW
    float x1 = (px - pw * 0.5f) / 76.0f * 608.0f;
    float y1 = (py - ph * 0.5f) / 76.0f * 608.0f;
    float x2 = (px + pw * 0.5f) / 76.0f * 608.0f;
    float y2 = (py + ph * 0.5f) / 76.0f * 608.0f;
    float area2 = (x2 - x1) * (y2 - y1);
    float best = 0.0f;  // iou >= 0 always
#pragma unroll
    for (int m = 0; m < MM; ++m) {
        float4 gb = sbox[m];
        float area1 = (gb.z - gb.x) * (gb.w - gb.y);
        float ltx = fmaxf(gb.x, x1), lty = fmaxf(gb.y, y1);
        float rbx = fminf(gb.z, x2), rby = fminf(gb.w, y2);
        float inter = fmaxf(rbx - ltx, 0.0f) * fmaxf(rby - lty, 0.0f);
        float iou = inter * __builtin_amdgcn_rcpf(area1 + area2 - inter);
        best = fmaxf(best, iou);
    }
    noobj[idx] = (best <= 0.5f) ? 1.0f : 0.0f;
    obj[idx] = 0.0f;
}

// ---------------------------------------------------------------------------
// Kernel 3: per-GT best-anchor argmax (first-max tiebreak, exact fdiv kept to
// preserve argmax ordering). Idempotent constant scatter -> no atomics.
// ---------------------------------------------------------------------------
__global__ void assign_kernel(const float* __restrict__ gt,
                              float* __restrict__ noobj, float* __restrict__ obj) {
    int r = blockIdx.x * blockDim.x + threadIdx.x;
    if (r >= BB * MM) return;
    const float* g = gt + (size_t)r * 6;
    float cx = g[1], cy = g[2], gw = g[3], gh = g[4];
    float gx1 = (cx - gw * 0.5f) * 608.0f, gy1 = (cy - gh * 0.5f) * 608.0f;
    float gx2 = (cx + gw * 0.5f) * 608.0f, gy2 = (cy + gh * 0.5f) * 608.0f;
    float area_g = (gx2 - gx1) * (gy2 - gy1);
    int best = 0;
    float bestv = -1.0f;
#pragma unroll
    for (int k = 0; k < 9; ++k) {
        float ow = c_anchor[k][0] / 608.0f, oh = c_anchor[k][1] / 608.0f;
        float ax1 = (cx - ow * 0.5f) * 608.0f, ay1 = (cy - oh * 0.5f) * 608.0f;
        float ax2 = (cx + ow * 0.5f) * 608.0f, ay2 = (cy + oh * 0.5f) * 608.0f;
        float ltx = fmaxf(gx1, ax1), lty = fmaxf(gy1, ay1);
        float rbx = fminf(gx2, ax2), rby = fminf(gy2, ay2);
        float inter = fmaxf(rbx - ltx, 0.0f) * fmaxf(rby - lty, 0.0f);
        float area_a = (ax2 - ax1) * (ay2 - ay1);
        float v = inter / (area_g + area_a - inter);
        if (v > bestv) { bestv = v; best = k; }
    }
    if (best < AA) {
        int b = r / MM;  // reference uses row position, not the gt batch column
        int gi = (int)(cx * 76.0f);
        int gj = (int)(cy * 76.0f);
        int flat = ((b * AA + best) * WW + gi) * WW + gj;
        obj[flat] = 1.0f;
        noobj[flat] = 0.0f;
    }
}

extern "C" void kernel_launch(void* const* d_in, const int* in_sizes, int n_in,
                              void* d_out, int out_size, void* d_ws, size_t ws_size,
                              hipStream_t stream) {
    const float* pred = (const float*)d_in[0];
    const float* gt   = (const float*)d_in[1];
    float* dec   = (float*)d_out;            // 23,566,080
    float* noobj = dec + NDECODE;            //    277,248
    float* obj   = noobj + NCELLS;           //    277,248
    float* boxes = (float*)d_ws;             // NCELLS*4 floats = 4.4 MB scratch

    const int n4 = NDECODE / 4;              // 5,891,520, divisible by 4
    decode_kernel<<<(n4 + 255) / 256, 256, 0, stream>>>(pred, dec, boxes);

    dim3 gb((CELLS_PER_IMG + 255) / 256, BB);
    noobj_kernel<<<gb, 256, 0, stream>>>((const float4*)boxes, gt, noobj, obj);

    assign_kernel<<<2, 256, 0, stream>>>(gt, noobj, obj);
}